// Round 1
// baseline (5016.744 us; speedup 1.0000x reference)
//
#include <hip/hip_runtime.h>
#include <stdint.h>

// Farthest point sampling: b=16, n=65536, npoints=2048. Full-f64 decision
// pipeline (R5: harness ref is float64 ground-truth recompute; R5-R16 absmax 0).
//
// R17 = R16 (4.73 ms) + winner-coordinate fetch removed from the serial tail:
//  - At poll-success, each wave0 lane speculatively prefetches ITS slot's
//    candidate coords (P[l0&0xFFFF], 16 L2-resident lines); the loads overlap
//    the 4-stage butterfly. After the butterfly a ballot locates the winning
//    lane ((bd,bi) bit-match; candidate indices are unique across slots) and
//    3x v_readlane broadcasts its coords -> no dependent P[wi] L2 round-trip.
//  - LDS mailbox widened to 4 self-tagged words {idx|tag, x|tag, y|tag,
//    z|tag} stored by lanes 0..3 in one ds_write; waves 1..3 take coords
//    from LDS and skip their P[wi] fetch too.
// Everything else R16 verbatim: 16 blocks x 256 thr per batch; waves 1..3
// post (bd,bi) via 2 self-tagged b64 LDS words then wait on the parity
// mailbox; wave0 gathers via LDS tag-spin, combines, publishes ONE
// single-writer 64-B slot (w0=[bd_hi32|tag|idx] w1=[bd_lo32|tag|idx]),
// s_sleep(12) then polls with one global_load_dwordx4 sc0 sc1 per round
// (escalating to the proven agent atomic-pair spin after 32 rounds),
// own-slot register substitution, 4-stage butterfly. Parity double-buffer,
// unique 16-bit tags (poison 0 unmatchable), skew <= 1 iteration via the
// rendezvous chain extended through the LDS hop.

#define NBATCH   16
#define NPTS     65536
#define NPOINTS  2048
#define KBLK     16                  // blocks per batch == slots per batch
#define THREADS  256
#define PPB      4096                // points per block
#define PPT      16                  // points per thread
#define SLOT_U64 8                   // 64-B stride: single writer per line
#define REGION_U64 (KBLK * SLOT_U64) // 1 KB per (parity,batch)

#define TAGOK(w) (((unsigned)((w) >> 16) & 0xFFFFu) == tag)

typedef unsigned int uint4v __attribute__((ext_vector_type(4)));

// One 16-B device-coherent load covering both slot words.
__device__ __forceinline__ void load_slot16(const unsigned long long* p,
                                            unsigned long long& w0,
                                            unsigned long long& w1) {
    uint4v r;
    asm volatile("global_load_dwordx4 %0, %1, off sc0 sc1\n\t"
                 "s_waitcnt vmcnt(0)"
                 : "=v"(r) : "v"(p) : "memory");
    w0 = ((unsigned long long)r.y << 32) | r.x;
    w1 = ((unsigned long long)r.w << 32) | r.z;
}

__global__ __launch_bounds__(THREADS, 1)
void fps_kernel(const float* __restrict__ pts, int* __restrict__ out,
                unsigned long long* __restrict__ slots)
{
    const int bid  = blockIdx.x;
    const int g    = bid & 15;       // batch (XCD co-location swizzle)
    const int blk  = bid >> 4;       // block within batch, 0..15
    const int tid  = threadIdx.x;
    const int lane = tid & 63;
    const int wave = tid >> 6;       // 0..3

    const float* __restrict__ P = pts + (size_t)g * (NPTS * 3);

    // mailbox: [par][0]=idx|tag  [1]=x|tag  [2]=y|tag  [3]=z|tag
    __shared__ unsigned long long s_mail[2][4];
    __shared__ unsigned long long s_cand[2][3][2];  // waves 1..3 candidates

    // Register-resident coords (f32; exact when widened to f64) + f64 dist.
    float  x[PPT], y[PPT], z[PPT];
    double dist[PPT];
    const int base = blk * PPB;
#pragma unroll
    for (int j = 0; j < PPT; ++j) {
        const int idx = base + j * THREADS + tid;
        x[j] = P[idx * 3 + 0];
        y[j] = P[idx * 3 + 1];
        z[j] = P[idx * 3 + 2];
        dist[j] = 1e10;              // never survives iteration 0
    }
    if (tid < 12) ((unsigned long long*)s_cand)[tid] = 0ull;  // tags never 0
    if (tid < 8)  ((unsigned long long*)s_mail)[tid] = 0ull;
    __syncthreads();                 // once, before the loop

    double qx = (double)P[0], qy = (double)P[1], qz = (double)P[2];
    if (blk == 0 && tid == 0) out[g * NPOINTS] = 0;

    for (int it = 0; it < NPOINTS - 1; ++it) {
        // ---- f64 min-dist update + thread-local argmax (first-max) ----
        double bd = -1.0;
        int    bi = 0x7FFFFFFF;
        {
#pragma clang fp contract(off)
#pragma unroll
            for (int j = 0; j < PPT; ++j) {
                const double dx = (double)x[j] - qx;
                const double dy = (double)y[j] - qy;
                const double dz = (double)z[j] - qz;
                const double d  = (dx * dx + dy * dy) + dz * dz;
                const double nd = fmin(dist[j], d);
                dist[j] = nd;
                const bool t = nd > bd;          // strict: first-max kept
                bd = t ? nd : bd;
                bi = t ? (base + j * THREADS + tid) : bi;
            }
        }

        // ---- 64-lane butterfly argmax over (bd, bi) ----
#pragma unroll
        for (int m = 1; m < 64; m <<= 1) {
            const double od = __shfl_xor(bd, m, 64);
            const int    oi = __shfl_xor(bi, m, 64);
            const bool t = (od > bd) || (od == bd && oi < bi);
            bd = t ? od : bd; bi = t ? oi : bi;
        }

        const unsigned tag = (unsigned)(it + 1);
        const int par = it & 1;
        unsigned long long* rb =
            slots + (size_t)(par * NBATCH + g) * REGION_U64;

        float qxf, qyf, qzf;         // this iteration's winner coords (f32)

        if (wave != 0) {
            // ---- post candidate to LDS (2 self-tagged b64 words) ----
            if (lane == 0) {
                const unsigned long long B =
                    (unsigned long long)__double_as_longlong(bd);
                const unsigned long long TI =
                      ((unsigned long long)tag << 16)
                    | (unsigned long long)((unsigned)bi & 0xFFFFu);
                __hip_atomic_store(&s_cand[par][wave - 1][0],
                                   ((B >> 32) << 32) | TI,
                                   __ATOMIC_RELAXED,
                                   __HIP_MEMORY_SCOPE_WORKGROUP);
                __hip_atomic_store(&s_cand[par][wave - 1][1],
                                   ((B & 0xFFFFFFFFull) << 32) | TI,
                                   __ATOMIC_RELAXED,
                                   __HIP_MEMORY_SCOPE_WORKGROUP);
            }
            // ---- wait for the iteration result on the LDS mailbox ----
            unsigned long long fv;
            int guard = 0;
            do {
                fv = __hip_atomic_load(&s_mail[par][0], __ATOMIC_RELAXED,
                                       __HIP_MEMORY_SCOPE_WORKGROUP);
            } while (((unsigned)fv != tag) && ++guard < (1 << 20));
            // ---- winner coords straight from LDS (self-tagged words) ----
            unsigned long long f1, f2, f3;
            int gq = 0;
            bool okm;
            do {
                f1 = __hip_atomic_load(&s_mail[par][1], __ATOMIC_RELAXED,
                                       __HIP_MEMORY_SCOPE_WORKGROUP);
                f2 = __hip_atomic_load(&s_mail[par][2], __ATOMIC_RELAXED,
                                       __HIP_MEMORY_SCOPE_WORKGROUP);
                f3 = __hip_atomic_load(&s_mail[par][3], __ATOMIC_RELAXED,
                                       __HIP_MEMORY_SCOPE_WORKGROUP);
                okm = ((unsigned)f1 == tag) & ((unsigned)f2 == tag)
                    & ((unsigned)f3 == tag);
            } while (!okm && ++gq < (1 << 20));
            qxf = __int_as_float((int)(f1 >> 32));
            qyf = __int_as_float((int)(f2 >> 32));
            qzf = __int_as_float((int)(f3 >> 32));
        } else {
            // ---- wave0: gather waves 1..3 from LDS (tag-gated spin) ----
            unsigned long long c[3][2];
            {
                int guard = 0;
                bool all;
                do {
                    all = true;
#pragma unroll
                    for (int w = 0; w < 3; ++w) {
                        c[w][0] = __hip_atomic_load(&s_cand[par][w][0],
                                      __ATOMIC_RELAXED,
                                      __HIP_MEMORY_SCOPE_WORKGROUP);
                        c[w][1] = __hip_atomic_load(&s_cand[par][w][1],
                                      __ATOMIC_RELAXED,
                                      __HIP_MEMORY_SCOPE_WORKGROUP);
                        all = all & TAGOK(c[w][0]) & TAGOK(c[w][1]);
                    }
                } while (!all && ++guard < (1 << 20));
            }
            // combine 3 + own (lane-uniform; every lane redundantly)
#pragma unroll
            for (int w = 0; w < 3; ++w) {
                const double od = __longlong_as_double((long long)(
                    ((c[w][0] >> 32) << 32) | (c[w][1] >> 32)));
                const int    oi = (int)(c[w][0] & 0xFFFFull);
                const bool t = (od > bd) || (od == bd && oi < bi);
                bd = t ? od : bd; bi = t ? oi : bi;
            }

            // block candidate words (used for publish AND own-slot subst.)
            const unsigned long long B =
                (unsigned long long)__double_as_longlong(bd);
            const unsigned long long TI =
                  ((unsigned long long)tag << 16)
                | (unsigned long long)((unsigned)bi & 0xFFFFu);
            const unsigned long long own0 = ((B >> 32) << 32) | TI;
            const unsigned long long own1 = ((B & 0xFFFFFFFFull) << 32) | TI;

            // ---- publish the block's slot (lanes 0..1) ----
            if (lane < 2) {
                __hip_atomic_store(rb + blk * SLOT_U64 + lane,
                                   (lane == 0) ? own0 : own1,
                                   __ATOMIC_RELAXED,
                                   __HIP_MEMORY_SCOPE_AGENT);
            }

            // ---- poll: lane i watches slot i&15, EXCEPT its own block's
            //      slot which comes from registers (tag trivially valid).
            //      15 lines/round; sleep tuned to store-visible latency ----
            unsigned long long* sp = rb + (lane & 15) * SLOT_U64;
            const bool own = ((lane & 15) == blk);
            unsigned long long l0 = own0, l1 = own1;
            bool ok = own;
            __builtin_amdgcn_s_sleep(12);  // ~768 cy: skip guaranteed-miss rounds
            int g1 = 0;
            while (!ok && g1 < 32) {
                load_slot16(sp, l0, l1);
                ok = TAGOK(l0) & TAGOK(l1);
                ++g1;
            }
            int g2 = 0;
            while (!ok) {
                // escalation: proven agent atomic-pair spin
                l0 = __hip_atomic_load(sp + 0, __ATOMIC_RELAXED,
                                       __HIP_MEMORY_SCOPE_AGENT);
                l1 = __hip_atomic_load(sp + 1, __ATOMIC_RELAXED,
                                       __HIP_MEMORY_SCOPE_AGENT);
                ok = TAGOK(l0) & TAGOK(l1);
                if (++g2 > (1 << 20)) break;   // fail loud, never hang
            }

            double cd = __longlong_as_double(
                (long long)(((l0 >> 32) << 32) | (l1 >> 32)));
            int    ci = (int)(l0 & 0xFFFFull);

            // ---- speculative prefetch of THIS lane's candidate coords:
            //      issued before the butterfly, latency hides under it ----
            const double sd = cd;
            const int    si = ci;
            const float* pc = P + (size_t)(unsigned)si * 3;
            const float px = pc[0];
            const float py = pc[1];
            const float pz = pc[2];

            // ---- 4-stage butterfly within each 16-lane group ----
#pragma unroll
            for (int m = 1; m < 16; m <<= 1) {
                const double od = __shfl_xor(cd, m, 64);
                const int    oi = __shfl_xor(ci, m, 64);
                const bool t = (od > cd) || (od == cd && oi < ci);
                cd = t ? od : cd; ci = t ? oi : ci;
            }

            // ---- winning lane -> broadcast its prefetched coords.
            //      Candidate indices are unique across slots (disjoint
            //      point ranges), so the bit-match is unambiguous. ----
            const bool match =
                (__double_as_longlong(sd) == __double_as_longlong(cd))
                & (si == ci);
            const unsigned long long mb = __ballot(match);
            const int wl = (__ffsll(mb) - 1) & 63;
            qxf = __int_as_float(
                __builtin_amdgcn_readlane(__float_as_int(px), wl));
            qyf = __int_as_float(
                __builtin_amdgcn_readlane(__float_as_int(py), wl));
            qzf = __int_as_float(
                __builtin_amdgcn_readlane(__float_as_int(pz), wl));

            // ---- LDS mailbox: 4 tagged words in one ds_write (lanes 0..3)
            if (lane < 4) {
                const unsigned long long v =
                    (lane == 0)
                      ? (((unsigned long long)(unsigned)ci << 32)
                         | (unsigned long long)tag)
                  : (lane == 1)
                      ? (((unsigned long long)(unsigned)__float_as_int(qxf) << 32)
                         | (unsigned long long)tag)
                  : (lane == 2)
                      ? (((unsigned long long)(unsigned)__float_as_int(qyf) << 32)
                         | (unsigned long long)tag)
                      : (((unsigned long long)(unsigned)__float_as_int(qzf) << 32)
                         | (unsigned long long)tag);
                __hip_atomic_store(&s_mail[par][lane], v,
                                   __ATOMIC_RELAXED,
                                   __HIP_MEMORY_SCOPE_WORKGROUP);
            }
            if (lane == 0 && blk == 0) out[g * NPOINTS + it + 1] = ci;
        }

        // ---- winner coords now come from registers/LDS, no P[wi] fetch ----
        qx = (double)qxf; qy = (double)qyf; qz = (double)qzf;
    }
}

extern "C" void kernel_launch(void* const* d_in, const int* in_sizes, int n_in,
                              void* d_out, int out_size, void* d_ws, size_t ws_size,
                              hipStream_t stream) {
    (void)in_sizes; (void)n_in; (void)out_size; (void)ws_size;
    // d_in[0] = npoints (scalar, fixed 2048 per setup), d_in[1] = t_in
    const float* t_in = (const float*)d_in[1];
    int* out = (int*)d_out;
    unsigned long long* slots = (unsigned long long*)d_ws;  // 32 KB used

    dim3 grid(NBATCH * KBLK);
    dim3 block(THREADS);
    void* args[] = { (void*)&t_in, (void*)&out, (void*)&slots };
    hipLaunchCooperativeKernel((const void*)fps_kernel, grid, block, args, 0, stream);
}

// Round 2
// 4770.689 us; speedup vs baseline: 1.0516x; 1.0516x over previous
//
#include <hip/hip_runtime.h>
#include <stdint.h>

// Farthest point sampling: b=16, n=65536, npoints=2048. Full-f64 decision
// pipeline (R5: harness ref is float64 ground-truth recompute; R5-R16 absmax 0).
//
// R18 = R16 (4.73 ms) + coordinate broadcast, rendezvous-neutral this time.
// R17's regression (+140cy/iter) was self-inflicted: it delayed the mailbox
// rendezvous word behind the vmcnt+ballot+readlane chain. R18 keeps the
// prefetch idea but never delays the rendezvous:
//  - At poll-success each wave0 lane speculatively prefetches ITS watched
//    slot's candidate coords (issue BEFORE the 4-stage butterfly; ~220cy of
//    dependent ds_bpermute covers the ~200cy L2 hit).
//  - After the butterfly, ballot on (si == ci) finds the winning lane
//    (candidate indices unique across slots); 3x v_readlane broadcasts its
//    already-landed coords. No dependent P[wi] round-trip for wave0.
//  - Waves 1..3 need ONLY coords, not the index: wave0 lanes 0..2 store
//    three self-tagged coord words {x|tag, y|tag, z|tag} in one ds_write;
//    waves 1..3 spin directly on those (single LDS round, ~130cy after
//    butterfly-end vs ~260cy for R16's P[wi] L2 fetch).
// Everything else R16 verbatim: 16 blocks x 256 thr per batch; waves 1..3
// post (bd,bi) via 2 self-tagged b64 LDS words; wave0 gathers via LDS
// tag-spin, combines, publishes ONE single-writer 64-B slot
// (w0=[bd_hi32|tag|idx] w1=[bd_lo32|tag|idx]), s_sleep(12) then polls with
// one global_load_dwordx4 sc0 sc1 per round (escalating to the agent
// atomic-pair spin after 32 rounds), own-slot register substitution,
// 4-stage butterfly. Parity double-buffer, unique 16-bit tags, skew <= 1
// iteration via the rendezvous chain extended through the LDS hop.

#define NBATCH   16
#define NPTS     65536
#define NPOINTS  2048
#define KBLK     16                  // blocks per batch == slots per batch
#define THREADS  256
#define PPB      4096                // points per block
#define PPT      16                  // points per thread
#define SLOT_U64 8                   // 64-B stride: single writer per line
#define REGION_U64 (KBLK * SLOT_U64) // 1 KB per (parity,batch)

#define TAGOK(w) (((unsigned)((w) >> 16) & 0xFFFFu) == tag)

typedef unsigned int uint4v __attribute__((ext_vector_type(4)));

// One 16-B device-coherent load covering both slot words.
__device__ __forceinline__ void load_slot16(const unsigned long long* p,
                                            unsigned long long& w0,
                                            unsigned long long& w1) {
    uint4v r;
    asm volatile("global_load_dwordx4 %0, %1, off sc0 sc1\n\t"
                 "s_waitcnt vmcnt(0)"
                 : "=v"(r) : "v"(p) : "memory");
    w0 = ((unsigned long long)r.y << 32) | r.x;
    w1 = ((unsigned long long)r.w << 32) | r.z;
}

__global__ __launch_bounds__(THREADS, 1)
void fps_kernel(const float* __restrict__ pts, int* __restrict__ out,
                unsigned long long* __restrict__ slots)
{
    const int bid  = blockIdx.x;
    const int g    = bid & 15;       // batch (XCD co-location swizzle)
    const int blk  = bid >> 4;       // block within batch, 0..15
    const int tid  = threadIdx.x;
    const int lane = tid & 63;
    const int wave = tid >> 6;       // 0..3

    const float* __restrict__ P = pts + (size_t)g * (NPTS * 3);

    // mailbox: [par][k] = coord_k|tag for k=0,1,2 (x,y,z); [3] unused pad
    __shared__ unsigned long long s_mail[2][4];
    __shared__ unsigned long long s_cand[2][3][2];  // waves 1..3 candidates

    // Register-resident coords (f32; exact when widened to f64) + f64 dist.
    float  x[PPT], y[PPT], z[PPT];
    double dist[PPT];
    const int base = blk * PPB;
#pragma unroll
    for (int j = 0; j < PPT; ++j) {
        const int idx = base + j * THREADS + tid;
        x[j] = P[idx * 3 + 0];
        y[j] = P[idx * 3 + 1];
        z[j] = P[idx * 3 + 2];
        dist[j] = 1e10;              // never survives iteration 0
    }
    if (tid < 12) ((unsigned long long*)s_cand)[tid] = 0ull;  // tags never 0
    if (tid < 8)  ((unsigned long long*)s_mail)[tid] = 0ull;
    __syncthreads();                 // once, before the loop

    double qx = (double)P[0], qy = (double)P[1], qz = (double)P[2];
    if (blk == 0 && tid == 0) out[g * NPOINTS] = 0;

    for (int it = 0; it < NPOINTS - 1; ++it) {
        // ---- f64 min-dist update + thread-local argmax (first-max) ----
        double bd = -1.0;
        int    bi = 0x7FFFFFFF;
        {
#pragma clang fp contract(off)
#pragma unroll
            for (int j = 0; j < PPT; ++j) {
                const double dx = (double)x[j] - qx;
                const double dy = (double)y[j] - qy;
                const double dz = (double)z[j] - qz;
                const double d  = (dx * dx + dy * dy) + dz * dz;
                const double nd = fmin(dist[j], d);
                dist[j] = nd;
                const bool t = nd > bd;          // strict: first-max kept
                bd = t ? nd : bd;
                bi = t ? (base + j * THREADS + tid) : bi;
            }
        }

        // ---- 64-lane butterfly argmax over (bd, bi) ----
#pragma unroll
        for (int m = 1; m < 64; m <<= 1) {
            const double od = __shfl_xor(bd, m, 64);
            const int    oi = __shfl_xor(bi, m, 64);
            const bool t = (od > bd) || (od == bd && oi < bi);
            bd = t ? od : bd; bi = t ? oi : bi;
        }

        const unsigned tag = (unsigned)(it + 1);
        const int par = it & 1;
        unsigned long long* rb =
            slots + (size_t)(par * NBATCH + g) * REGION_U64;

        float qxf, qyf, qzf;         // this iteration's winner coords (f32)

        if (wave != 0) {
            // ---- post candidate to LDS (2 self-tagged b64 words) ----
            if (lane == 0) {
                const unsigned long long B =
                    (unsigned long long)__double_as_longlong(bd);
                const unsigned long long TI =
                      ((unsigned long long)tag << 16)
                    | (unsigned long long)((unsigned)bi & 0xFFFFu);
                __hip_atomic_store(&s_cand[par][wave - 1][0],
                                   ((B >> 32) << 32) | TI,
                                   __ATOMIC_RELAXED,
                                   __HIP_MEMORY_SCOPE_WORKGROUP);
                __hip_atomic_store(&s_cand[par][wave - 1][1],
                                   ((B & 0xFFFFFFFFull) << 32) | TI,
                                   __ATOMIC_RELAXED,
                                   __HIP_MEMORY_SCOPE_WORKGROUP);
            }
            // ---- winner coords straight from LDS (3 self-tagged words).
            //      This IS the rendezvous: tags == it+1 only when wave0 of
            //      this iteration has broadcast. Parity leftovers carry
            //      tag it-1 -> no false positive. ----
            unsigned long long f1, f2, f3;
            int guard = 0;
            bool okm;
            do {
                f1 = __hip_atomic_load(&s_mail[par][0], __ATOMIC_RELAXED,
                                       __HIP_MEMORY_SCOPE_WORKGROUP);
                f2 = __hip_atomic_load(&s_mail[par][1], __ATOMIC_RELAXED,
                                       __HIP_MEMORY_SCOPE_WORKGROUP);
                f3 = __hip_atomic_load(&s_mail[par][2], __ATOMIC_RELAXED,
                                       __HIP_MEMORY_SCOPE_WORKGROUP);
                okm = ((unsigned)f1 == tag) & ((unsigned)f2 == tag)
                    & ((unsigned)f3 == tag);
            } while (!okm && ++guard < (1 << 20));
            qxf = __int_as_float((int)(f1 >> 32));
            qyf = __int_as_float((int)(f2 >> 32));
            qzf = __int_as_float((int)(f3 >> 32));
        } else {
            // ---- wave0: gather waves 1..3 from LDS (tag-gated spin) ----
            unsigned long long c[3][2];
            {
                int guard = 0;
                bool all;
                do {
                    all = true;
#pragma unroll
                    for (int w = 0; w < 3; ++w) {
                        c[w][0] = __hip_atomic_load(&s_cand[par][w][0],
                                      __ATOMIC_RELAXED,
                                      __HIP_MEMORY_SCOPE_WORKGROUP);
                        c[w][1] = __hip_atomic_load(&s_cand[par][w][1],
                                      __ATOMIC_RELAXED,
                                      __HIP_MEMORY_SCOPE_WORKGROUP);
                        all = all & TAGOK(c[w][0]) & TAGOK(c[w][1]);
                    }
                } while (!all && ++guard < (1 << 20));
            }
            // combine 3 + own (lane-uniform; every lane redundantly)
#pragma unroll
            for (int w = 0; w < 3; ++w) {
                const double od = __longlong_as_double((long long)(
                    ((c[w][0] >> 32) << 32) | (c[w][1] >> 32)));
                const int    oi = (int)(c[w][0] & 0xFFFFull);
                const bool t = (od > bd) || (od == bd && oi < bi);
                bd = t ? od : bd; bi = t ? oi : bi;
            }

            // block candidate words (used for publish AND own-slot subst.)
            const unsigned long long B =
                (unsigned long long)__double_as_longlong(bd);
            const unsigned long long TI =
                  ((unsigned long long)tag << 16)
                | (unsigned long long)((unsigned)bi & 0xFFFFu);
            const unsigned long long own0 = ((B >> 32) << 32) | TI;
            const unsigned long long own1 = ((B & 0xFFFFFFFFull) << 32) | TI;

            // ---- publish the block's slot (lanes 0..1) ----
            if (lane < 2) {
                __hip_atomic_store(rb + blk * SLOT_U64 + lane,
                                   (lane == 0) ? own0 : own1,
                                   __ATOMIC_RELAXED,
                                   __HIP_MEMORY_SCOPE_AGENT);
            }

            // ---- poll: lane i watches slot i&15, EXCEPT its own block's
            //      slot which comes from registers (tag trivially valid).
            //      15 lines/round; sleep tuned to store-visible latency ----
            unsigned long long* sp = rb + (lane & 15) * SLOT_U64;
            const bool own = ((lane & 15) == blk);
            unsigned long long l0 = own0, l1 = own1;
            bool ok = own;
            __builtin_amdgcn_s_sleep(12);  // ~768 cy: skip guaranteed-miss rounds
            int g1 = 0;
            while (!ok && g1 < 32) {
                load_slot16(sp, l0, l1);
                ok = TAGOK(l0) & TAGOK(l1);
                ++g1;
            }
            int g2 = 0;
            while (!ok) {
                // escalation: proven agent atomic-pair spin
                l0 = __hip_atomic_load(sp + 0, __ATOMIC_RELAXED,
                                       __HIP_MEMORY_SCOPE_AGENT);
                l1 = __hip_atomic_load(sp + 1, __ATOMIC_RELAXED,
                                       __HIP_MEMORY_SCOPE_AGENT);
                ok = TAGOK(l0) & TAGOK(l1);
                if (++g2 > (1 << 20)) break;   // fail loud, never hang
            }

            double cd = __longlong_as_double(
                (long long)(((l0 >> 32) << 32) | (l1 >> 32)));
            int    ci = (int)(l0 & 0xFFFFull);

            // ---- speculative prefetch of THIS lane's candidate coords:
            //      issued before the butterfly; ~220cy of dependent
            //      ds_bpermute stages cover the ~200cy L2 hit, so the
            //      vmcnt wait at readlane is ~free ----
            const int    si = ci;
            const float* pc = P + (size_t)(unsigned)si * 3;
            const float px = pc[0];
            const float py = pc[1];
            const float pz = pc[2];

            // ---- 4-stage butterfly within each 16-lane group ----
#pragma unroll
            for (int m = 1; m < 16; m <<= 1) {
                const double od = __shfl_xor(cd, m, 64);
                const int    oi = __shfl_xor(ci, m, 64);
                const bool t = (od > cd) || (od == cd && oi < ci);
                cd = t ? od : cd; ci = t ? oi : ci;
            }

            // ---- out write: independent of the coord chain ----
            if (lane == 0 && blk == 0) out[g * NPOINTS + it + 1] = ci;

            // ---- winning lane -> broadcast its prefetched coords.
            //      Candidate indices are unique across slots (disjoint
            //      point ranges), so si==ci identifies exactly the lanes
            //      that prefetched the winner. ----
            const unsigned long long mb = __ballot(si == ci);
            const int wl = (__ffsll(mb) - 1) & 63;
            qxf = __int_as_float(
                __builtin_amdgcn_readlane(__float_as_int(px), wl));
            qyf = __int_as_float(
                __builtin_amdgcn_readlane(__float_as_int(py), wl));
            qzf = __int_as_float(
                __builtin_amdgcn_readlane(__float_as_int(pz), wl));

            // ---- LDS mailbox: 3 tagged coord words in one ds_write ----
            if (lane < 3) {
                const unsigned coord =
                    (lane == 0) ? (unsigned)__float_as_int(qxf)
                  : (lane == 1) ? (unsigned)__float_as_int(qyf)
                                : (unsigned)__float_as_int(qzf);
                __hip_atomic_store(&s_mail[par][lane],
                                   ((unsigned long long)coord << 32)
                                 | (unsigned long long)tag,
                                   __ATOMIC_RELAXED,
                                   __HIP_MEMORY_SCOPE_WORKGROUP);
            }
        }

        // ---- winner coords from registers/LDS; no dependent P[wi] fetch ----
        qx = (double)qxf; qy = (double)qyf; qz = (double)qzf;
    }
}

extern "C" void kernel_launch(void* const* d_in, const int* in_sizes, int n_in,
                              void* d_out, int out_size, void* d_ws, size_t ws_size,
                              hipStream_t stream) {
    (void)in_sizes; (void)n_in; (void)out_size; (void)ws_size;
    // d_in[0] = npoints (scalar, fixed 2048 per setup), d_in[1] = t_in
    const float* t_in = (const float*)d_in[1];
    int* out = (int*)d_out;
    unsigned long long* slots = (unsigned long long*)d_ws;  // 32 KB used

    dim3 grid(NBATCH * KBLK);
    dim3 block(THREADS);
    void* args[] = { (void*)&t_in, (void*)&out, (void*)&slots };
    hipLaunchCooperativeKernel((const void*)fps_kernel, grid, block, args, 0, stream);
}

// Round 3
// 4430.735 us; speedup vs baseline: 1.1323x; 1.0767x over previous
//
#include <hip/hip_runtime.h>
#include <stdint.h>

// Farthest point sampling: b=16, n=65536, npoints=2048. Full-f64 decision
// pipeline (R5: harness ref is float64 ground-truth recompute; R5-R18 absmax 0).
//
// R19 = R18 + two cuts on the PUBLISH chain (R17 proved it is the critical
// path; R18 proved the coord-delivery tail is insensitive):
//  1. Pre-widened f64 coords (xd/yd/zd[16] converted once at load): removes
//     3x v_cvt_f64_f32 per point per iteration (~190cy/iter) from every
//     wave's update. Identical f64 arithmetic and rounding.
//  2. Per-wave publish with 16-B sub-slots, 4 per 64-B line: each wave's
//     lanes 0..1 store its own (bd,bi) quarter straight after its own
//     64-lane butterfly. The intra-block funnel (waves1-3 LDS post ->
//     wave0 gather spin -> combine) is deleted (~150-250cy off the publish
//     chain). All 4 writers of a line are waves of the SAME CU (no cross-CU
//     false sharing; 16-B quarters = single L3 sectors). Wave0's poll: lane
//     i watches quarter i of 64 at 16-B stride -> SAME 16 lines / same poll
//     traffic as R16 (R12's law not provoked); 6-stage butterfly (2 extra
//     stages on the insensitive detect tail). Candidate indices stay unique
//     across all 64 quarters (disjoint tid partitions), so the R18
//     prefetch -> ballot(si==ci) -> readlane -> coords-mailbox tail ports
//     verbatim. Skew<=1 / parity / tag discipline unchanged: every quarter
//     writer at it+2 is transitively behind every reader of parity p at it.
// Everything else R18 verbatim: s_sleep(12) then 32 rounds of one
// global_load_dwordx4 sc0 sc1 per lane (escalating to the proven agent
// atomic-pair spin), own-quarter register substitution (lane blk*4),
// waves1-3 spin on 3 self-tagged LDS coord words {x|tag,y|tag,z|tag}.

#define NBATCH   16
#define NPTS     65536
#define NPOINTS  2048
#define KBLK     16                  // blocks per batch
#define THREADS  256
#define PPB      4096                // points per block
#define PPT      16                  // points per thread
#define QPB      4                   // quarters (waves) per block
#define SLOT_U64 2                   // 16 B per wave-quarter
#define REGION_U64 (KBLK * QPB * SLOT_U64) // 128 u64 = 1 KB per (parity,batch)

#define TAGOK(w) (((unsigned)((w) >> 16) & 0xFFFFu) == tag)

typedef unsigned int uint4v __attribute__((ext_vector_type(4)));

// One 16-B device-coherent load covering both quarter words.
__device__ __forceinline__ void load_slot16(const unsigned long long* p,
                                            unsigned long long& w0,
                                            unsigned long long& w1) {
    uint4v r;
    asm volatile("global_load_dwordx4 %0, %1, off sc0 sc1\n\t"
                 "s_waitcnt vmcnt(0)"
                 : "=v"(r) : "v"(p) : "memory");
    w0 = ((unsigned long long)r.y << 32) | r.x;
    w1 = ((unsigned long long)r.w << 32) | r.z;
}

__global__ __launch_bounds__(THREADS, 1)
void fps_kernel(const float* __restrict__ pts, int* __restrict__ out,
                unsigned long long* __restrict__ slots)
{
    const int bid  = blockIdx.x;
    const int g    = bid & 15;       // batch (XCD co-location swizzle)
    const int blk  = bid >> 4;       // block within batch, 0..15
    const int tid  = threadIdx.x;
    const int lane = tid & 63;
    const int wave = tid >> 6;       // 0..3

    const float* __restrict__ P = pts + (size_t)g * (NPTS * 3);

    // mailbox: [par][k] = coord_k|tag for k=0,1,2 (x,y,z); [3] unused pad
    __shared__ unsigned long long s_mail[2][4];

    // Pre-widened f64 coords (cvt paid ONCE, not per iteration) + f64 dist.
    double xd[PPT], yd[PPT], zd[PPT], dist[PPT];
    const int base = blk * PPB;
#pragma unroll
    for (int j = 0; j < PPT; ++j) {
        const int idx = base + j * THREADS + tid;
        xd[j] = (double)P[idx * 3 + 0];
        yd[j] = (double)P[idx * 3 + 1];
        zd[j] = (double)P[idx * 3 + 2];
        dist[j] = 1e10;              // never survives iteration 0
    }
    if (tid < 8) ((unsigned long long*)s_mail)[tid] = 0ull;  // tags never 0
    __syncthreads();                 // once, before the loop

    double qx = (double)P[0], qy = (double)P[1], qz = (double)P[2];
    if (blk == 0 && tid == 0) out[g * NPOINTS] = 0;

    for (int it = 0; it < NPOINTS - 1; ++it) {
        // ---- f64 min-dist update + thread-local argmax (first-max) ----
        double bd = -1.0;
        int    bi = 0x7FFFFFFF;
        {
#pragma clang fp contract(off)
#pragma unroll
            for (int j = 0; j < PPT; ++j) {
                const double dx = xd[j] - qx;
                const double dy = yd[j] - qy;
                const double dz = zd[j] - qz;
                const double d  = (dx * dx + dy * dy) + dz * dz;
                const double nd = fmin(dist[j], d);
                dist[j] = nd;
                const bool t = nd > bd;          // strict: first-max kept
                bd = t ? nd : bd;
                bi = t ? (base + j * THREADS + tid) : bi;
            }
        }

        // ---- 64-lane butterfly argmax over (bd, bi) ----
#pragma unroll
        for (int m = 1; m < 64; m <<= 1) {
            const double od = __shfl_xor(bd, m, 64);
            const int    oi = __shfl_xor(bi, m, 64);
            const bool t = (od > bd) || (od == bd && oi < bi);
            bd = t ? od : bd; bi = t ? oi : bi;
        }

        const unsigned tag = (unsigned)(it + 1);
        const int par = it & 1;
        unsigned long long* rb =
            slots + (size_t)(par * NBATCH + g) * REGION_U64;

        // ---- this wave's quarter words (publish + own substitution) ----
        const unsigned long long B =
            (unsigned long long)__double_as_longlong(bd);
        const unsigned long long TI =
              ((unsigned long long)tag << 16)
            | (unsigned long long)((unsigned)bi & 0xFFFFu);
        const unsigned long long own0 = ((B >> 32) << 32) | TI;
        const unsigned long long own1 = ((B & 0xFFFFFFFFull) << 32) | TI;

        // ---- per-wave publish: straight from butterfly to global store,
        //      no LDS post / gather / combine funnel ----
        if (lane < 2) {
            __hip_atomic_store(rb + (blk * QPB + wave) * SLOT_U64 + lane,
                               (lane == 0) ? own0 : own1,
                               __ATOMIC_RELAXED,
                               __HIP_MEMORY_SCOPE_AGENT);
        }

        float qxf, qyf, qzf;         // this iteration's winner coords (f32)

        if (wave != 0) {
            // ---- winner coords from LDS (3 self-tagged words). This IS
            //      the rendezvous: tags==it+1 only after wave0 broadcast;
            //      parity leftovers carry tag it-1 -> no false positive ----
            unsigned long long f1, f2, f3;
            int guard = 0;
            bool okm;
            do {
                f1 = __hip_atomic_load(&s_mail[par][0], __ATOMIC_RELAXED,
                                       __HIP_MEMORY_SCOPE_WORKGROUP);
                f2 = __hip_atomic_load(&s_mail[par][1], __ATOMIC_RELAXED,
                                       __HIP_MEMORY_SCOPE_WORKGROUP);
                f3 = __hip_atomic_load(&s_mail[par][2], __ATOMIC_RELAXED,
                                       __HIP_MEMORY_SCOPE_WORKGROUP);
                okm = ((unsigned)f1 == tag) & ((unsigned)f2 == tag)
                    & ((unsigned)f3 == tag);
            } while (!okm && ++guard < (1 << 20));
            qxf = __int_as_float((int)(f1 >> 32));
            qyf = __int_as_float((int)(f2 >> 32));
            qzf = __int_as_float((int)(f3 >> 32));
        } else {
            // ---- wave0: poll all 64 quarters, lane i watches quarter i
            //      (16-B stride, contiguous 1 KB = same 16 lines as R16).
            //      Own quarter (lane == blk*4) from registers. ----
            unsigned long long* sp = rb + lane * SLOT_U64;
            const bool own = (lane == blk * QPB);
            unsigned long long l0 = own0, l1 = own1;
            bool ok = own;
            __builtin_amdgcn_s_sleep(12);  // ~768 cy: skip guaranteed-miss rounds
            int g1 = 0;
            while (!ok && g1 < 32) {
                load_slot16(sp, l0, l1);
                ok = TAGOK(l0) & TAGOK(l1);
                ++g1;
            }
            int g2 = 0;
            while (!ok) {
                // escalation: proven agent atomic-pair spin
                l0 = __hip_atomic_load(sp + 0, __ATOMIC_RELAXED,
                                       __HIP_MEMORY_SCOPE_AGENT);
                l1 = __hip_atomic_load(sp + 1, __ATOMIC_RELAXED,
                                       __HIP_MEMORY_SCOPE_AGENT);
                ok = TAGOK(l0) & TAGOK(l1);
                if (++g2 > (1 << 20)) break;   // fail loud, never hang
            }

            double cd = __longlong_as_double(
                (long long)(((l0 >> 32) << 32) | (l1 >> 32)));
            int    ci = (int)(l0 & 0xFFFFull);

            // ---- speculative prefetch of THIS lane's candidate coords:
            //      issued before the butterfly; dependent ds stages cover
            //      the ~200cy L2 hit ----
            const int    si = ci;
            const float* pc = P + (size_t)(unsigned)si * 3;
            const float px = pc[0];
            const float py = pc[1];
            const float pz = pc[2];

            // ---- 6-stage butterfly over all 64 quarters ----
#pragma unroll
            for (int m = 1; m < 64; m <<= 1) {
                const double od = __shfl_xor(cd, m, 64);
                const int    oi = __shfl_xor(ci, m, 64);
                const bool t = (od > cd) || (od == cd && oi < ci);
                cd = t ? od : cd; ci = t ? oi : ci;
            }

            // ---- out write: independent of the coord chain ----
            if (lane == 0 && blk == 0) out[g * NPOINTS + it + 1] = ci;

            // ---- winning lane -> broadcast its prefetched coords.
            //      Candidate indices unique across all 64 quarters
            //      (disjoint tid partitions). ----
            const unsigned long long mb = __ballot(si == ci);
            const int wl = (__ffsll(mb) - 1) & 63;
            qxf = __int_as_float(
                __builtin_amdgcn_readlane(__float_as_int(px), wl));
            qyf = __int_as_float(
                __builtin_amdgcn_readlane(__float_as_int(py), wl));
            qzf = __int_as_float(
                __builtin_amdgcn_readlane(__float_as_int(pz), wl));

            // ---- LDS mailbox: 3 tagged coord words ----
            if (lane < 3) {
                const unsigned coord =
                    (lane == 0) ? (unsigned)__float_as_int(qxf)
                  : (lane == 1) ? (unsigned)__float_as_int(qyf)
                                : (unsigned)__float_as_int(qzf);
                __hip_atomic_store(&s_mail[par][lane],
                                   ((unsigned long long)coord << 32)
                                 | (unsigned long long)tag,
                                   __ATOMIC_RELAXED,
                                   __HIP_MEMORY_SCOPE_WORKGROUP);
            }
        }

        // ---- winner coords from registers/LDS; no dependent P[wi] fetch ----
        qx = (double)qxf; qy = (double)qyf; qz = (double)qzf;
    }
}

extern "C" void kernel_launch(void* const* d_in, const int* in_sizes, int n_in,
                              void* d_out, int out_size, void* d_ws, size_t ws_size,
                              hipStream_t stream) {
    (void)in_sizes; (void)n_in; (void)out_size; (void)ws_size;
    // d_in[0] = npoints (scalar, fixed 2048 per setup), d_in[1] = t_in
    const float* t_in = (const float*)d_in[1];
    int* out = (int*)d_out;
    unsigned long long* slots = (unsigned long long*)d_ws;  // 32 KB used

    dim3 grid(NBATCH * KBLK);
    dim3 block(THREADS);
    void* args[] = { (void*)&t_in, (void*)&out, (void*)&slots };
    hipLaunchCooperativeKernel((const void*)fps_kernel, grid, block, args, 0, stream);
}

// Round 4
// 4309.538 us; speedup vs baseline: 1.1641x; 1.0281x over previous
//
#include <hip/hip_runtime.h>
#include <stdint.h>

// Farthest point sampling: b=16, n=65536, npoints=2048. Full-f64 decision
// pipeline (R5: harness ref is float64 ground-truth recompute; R5-R19 absmax 0).
//
// R20 = R19 (4.43 ms) + DPP/permlane butterflies. R19's post-mortem left
// ~5195 cy/iter: update ~700, butterfly ~350, publish+LLC ~950, detect
// butterfly ~350, tail ~150. The two 6-stage __shfl_xor butterflies ran on
// ds_bpermute (3 words x ~50cy LDS latency per dependent stage). Replaced
// with VALU-speed transport, identical comparator/tie-break (bit-exact):
//   xor1  quad_perm 0xB1          (DPP, ~2cy/word)
//   xor2  quad_perm 0x4E          (DPP)
//   s3    row_half_mirror 0x141   (= i^7; valid once quads uniform -> 8-max)
//   s4    row_mirror 0x140        (= i^15; valid once 8-uniform -> 16-max)
//   xor16 ds_swizzle 0x401F       (single remaining LDS-latency stage)
//   xor32 permlane32_swap(v,v)    (partner = lane>=32 ? r[0] : r[1])
// Applied to BOTH the update-side butterfly (publish critical path of every
// wave) and wave0's detect-side butterfly. Everything else R19 verbatim:
// pre-widened f64 coords; per-wave publish of 16-B quarters (4/line, same-CU
// writers); wave0 polls 64 quarters (lane i watches quarter i, own-quarter
// register substitution), s_sleep(12) then 32 rounds of global_load_dwordx4
// sc0 sc1 escalating to agent atomic-pair spin; speculative coord prefetch
// + ballot(si==ci) + readlane broadcast; waves1-3 spin on 3 self-tagged LDS
// coord words. Parity double-buffer, unique 16-bit tags, skew<=1.

#define NBATCH   16
#define NPTS     65536
#define NPOINTS  2048
#define KBLK     16                  // blocks per batch
#define THREADS  256
#define PPB      4096                // points per block
#define PPT      16                  // points per thread
#define QPB      4                   // quarters (waves) per block
#define SLOT_U64 2                   // 16 B per wave-quarter
#define REGION_U64 (KBLK * QPB * SLOT_U64) // 128 u64 = 1 KB per (parity,batch)

#define TAGOK(w) (((unsigned)((w) >> 16) & 0xFFFFu) == tag)

typedef unsigned int uint4v __attribute__((ext_vector_type(4)));
typedef unsigned int uint2v __attribute__((ext_vector_type(2)));

// One 16-B device-coherent load covering both quarter words.
__device__ __forceinline__ void load_slot16(const unsigned long long* p,
                                            unsigned long long& w0,
                                            unsigned long long& w1) {
    uint4v r;
    asm volatile("global_load_dwordx4 %0, %1, off sc0 sc1\n\t"
                 "s_waitcnt vmcnt(0)"
                 : "=v"(r) : "v"(p) : "memory");
    w0 = ((unsigned long long)r.y << 32) | r.x;
    w1 = ((unsigned long long)r.w << 32) | r.z;
}

// ---- argmax butterfly stages: (d,i) <- winner of self and partner ----
__device__ __forceinline__ void red_combine(double& d, int& i,
                                            double od, int oi) {
    const bool t = (od > d) || (od == d && oi < i);
    d = t ? od : d; i = t ? oi : i;
}

template <int CTRL>
__device__ __forceinline__ void red_dpp(double& d, int& i) {
    const int hi = __double2hiint(d), lo = __double2loint(d);
    const int ohi = __builtin_amdgcn_update_dpp(hi, hi, CTRL, 0xF, 0xF, false);
    const int olo = __builtin_amdgcn_update_dpp(lo, lo, CTRL, 0xF, 0xF, false);
    const int oi  = __builtin_amdgcn_update_dpp(i,  i,  CTRL, 0xF, 0xF, false);
    red_combine(d, i, __hiloint2double(ohi, olo), oi);
}

__device__ __forceinline__ void red_swz16(double& d, int& i) {
    // ds_swizzle BitMode xor16: offset = (16<<10) | 0x1F = 0x401F
    const int ohi = __builtin_amdgcn_ds_swizzle(__double2hiint(d), 0x401F);
    const int olo = __builtin_amdgcn_ds_swizzle(__double2loint(d), 0x401F);
    const int oi  = __builtin_amdgcn_ds_swizzle(i, 0x401F);
    red_combine(d, i, __hiloint2double(ohi, olo), oi);
}

__device__ __forceinline__ void red_x32(double& d, int& i, bool hi_half) {
    // permlane32_swap(v,v): r[0][lane>=32] = v[lane-32], r[1][lane<32] =
    // v[lane+32] -> partner = hi_half ? r[0] : r[1].
    const unsigned hi = (unsigned)__double2hiint(d);
    const unsigned lo = (unsigned)__double2loint(d);
    uint2v rh = __builtin_amdgcn_permlane32_swap(hi, hi, false, false);
    uint2v rl = __builtin_amdgcn_permlane32_swap(lo, lo, false, false);
    uint2v ri = __builtin_amdgcn_permlane32_swap((unsigned)i, (unsigned)i,
                                                 false, false);
    const int ohi = (int)(hi_half ? rh[0] : rh[1]);
    const int olo = (int)(hi_half ? rl[0] : rl[1]);
    const int oi  = (int)(hi_half ? ri[0] : ri[1]);
    red_combine(d, i, __hiloint2double(ohi, olo), oi);
}

// Full 64-lane argmax (all lanes end with the global winner). Stage order
// matters: mirrors rely on prior quad/8-group uniformity.
__device__ __forceinline__ void argmax64(double& d, int& i, bool hi_half) {
    red_dpp<0xB1>(d, i);    // xor1  (quad_perm 1,0,3,2)
    red_dpp<0x4E>(d, i);    // xor2  (quad_perm 2,3,0,1)
    red_dpp<0x141>(d, i);   // i^7 row_half_mirror -> 8-max
    red_dpp<0x140>(d, i);   // i^15 row_mirror     -> 16-max
    red_swz16(d, i);        // xor16               -> 32-max
    red_x32(d, i, hi_half); // xor32               -> 64-max
}

__global__ __launch_bounds__(THREADS, 1)
void fps_kernel(const float* __restrict__ pts, int* __restrict__ out,
                unsigned long long* __restrict__ slots)
{
    const int bid  = blockIdx.x;
    const int g    = bid & 15;       // batch (XCD co-location swizzle)
    const int blk  = bid >> 4;       // block within batch, 0..15
    const int tid  = threadIdx.x;
    const int lane = tid & 63;
    const int wave = tid >> 6;       // 0..3
    const bool hi_half = (lane >= 32);

    const float* __restrict__ P = pts + (size_t)g * (NPTS * 3);

    // mailbox: [par][k] = coord_k|tag for k=0,1,2 (x,y,z); [3] unused pad
    __shared__ unsigned long long s_mail[2][4];

    // Pre-widened f64 coords (cvt paid ONCE, not per iteration) + f64 dist.
    double xd[PPT], yd[PPT], zd[PPT], dist[PPT];
    const int base = blk * PPB;
#pragma unroll
    for (int j = 0; j < PPT; ++j) {
        const int idx = base + j * THREADS + tid;
        xd[j] = (double)P[idx * 3 + 0];
        yd[j] = (double)P[idx * 3 + 1];
        zd[j] = (double)P[idx * 3 + 2];
        dist[j] = 1e10;              // never survives iteration 0
    }
    if (tid < 8) ((unsigned long long*)s_mail)[tid] = 0ull;  // tags never 0
    __syncthreads();                 // once, before the loop

    double qx = (double)P[0], qy = (double)P[1], qz = (double)P[2];
    if (blk == 0 && tid == 0) out[g * NPOINTS] = 0;

    for (int it = 0; it < NPOINTS - 1; ++it) {
        // ---- f64 min-dist update + thread-local argmax (first-max) ----
        double bd = -1.0;
        int    bi = 0x7FFFFFFF;
        {
#pragma clang fp contract(off)
#pragma unroll
            for (int j = 0; j < PPT; ++j) {
                const double dx = xd[j] - qx;
                const double dy = yd[j] - qy;
                const double dz = zd[j] - qz;
                const double d  = (dx * dx + dy * dy) + dz * dz;
                const double nd = fmin(dist[j], d);
                dist[j] = nd;
                const bool t = nd > bd;          // strict: first-max kept
                bd = t ? nd : bd;
                bi = t ? (base + j * THREADS + tid) : bi;
            }
        }

        // ---- 64-lane argmax butterfly (DPP/permlane transport) ----
        argmax64(bd, bi, hi_half);

        const unsigned tag = (unsigned)(it + 1);
        const int par = it & 1;
        unsigned long long* rb =
            slots + (size_t)(par * NBATCH + g) * REGION_U64;

        // ---- this wave's quarter words (publish + own substitution) ----
        const unsigned long long B =
            (unsigned long long)__double_as_longlong(bd);
        const unsigned long long TI =
              ((unsigned long long)tag << 16)
            | (unsigned long long)((unsigned)bi & 0xFFFFu);
        const unsigned long long own0 = ((B >> 32) << 32) | TI;
        const unsigned long long own1 = ((B & 0xFFFFFFFFull) << 32) | TI;

        // ---- per-wave publish: straight from butterfly to global store,
        //      no LDS post / gather / combine funnel ----
        if (lane < 2) {
            __hip_atomic_store(rb + (blk * QPB + wave) * SLOT_U64 + lane,
                               (lane == 0) ? own0 : own1,
                               __ATOMIC_RELAXED,
                               __HIP_MEMORY_SCOPE_AGENT);
        }

        float qxf, qyf, qzf;         // this iteration's winner coords (f32)

        if (wave != 0) {
            // ---- winner coords from LDS (3 self-tagged words). This IS
            //      the rendezvous: tags==it+1 only after wave0 broadcast;
            //      parity leftovers carry tag it-1 -> no false positive ----
            unsigned long long f1, f2, f3;
            int guard = 0;
            bool okm;
            do {
                f1 = __hip_atomic_load(&s_mail[par][0], __ATOMIC_RELAXED,
                                       __HIP_MEMORY_SCOPE_WORKGROUP);
                f2 = __hip_atomic_load(&s_mail[par][1], __ATOMIC_RELAXED,
                                       __HIP_MEMORY_SCOPE_WORKGROUP);
                f3 = __hip_atomic_load(&s_mail[par][2], __ATOMIC_RELAXED,
                                       __HIP_MEMORY_SCOPE_WORKGROUP);
                okm = ((unsigned)f1 == tag) & ((unsigned)f2 == tag)
                    & ((unsigned)f3 == tag);
            } while (!okm && ++guard < (1 << 20));
            qxf = __int_as_float((int)(f1 >> 32));
            qyf = __int_as_float((int)(f2 >> 32));
            qzf = __int_as_float((int)(f3 >> 32));
        } else {
            // ---- wave0: poll all 64 quarters, lane i watches quarter i
            //      (16-B stride, contiguous 1 KB = same 16 lines as R16).
            //      Own quarter (lane == blk*4) from registers. ----
            unsigned long long* sp = rb + lane * SLOT_U64;
            const bool own = (lane == blk * QPB);
            unsigned long long l0 = own0, l1 = own1;
            bool ok = own;
            __builtin_amdgcn_s_sleep(12);  // ~768 cy: skip guaranteed-miss rounds
            int g1 = 0;
            while (!ok && g1 < 32) {
                load_slot16(sp, l0, l1);
                ok = TAGOK(l0) & TAGOK(l1);
                ++g1;
            }
            int g2 = 0;
            while (!ok) {
                // escalation: proven agent atomic-pair spin
                l0 = __hip_atomic_load(sp + 0, __ATOMIC_RELAXED,
                                       __HIP_MEMORY_SCOPE_AGENT);
                l1 = __hip_atomic_load(sp + 1, __ATOMIC_RELAXED,
                                       __HIP_MEMORY_SCOPE_AGENT);
                ok = TAGOK(l0) & TAGOK(l1);
                if (++g2 > (1 << 20)) break;   // fail loud, never hang
            }

            double cd = __longlong_as_double(
                (long long)(((l0 >> 32) << 32) | (l1 >> 32)));
            int    ci = (int)(l0 & 0xFFFFull);

            // ---- speculative prefetch of THIS lane's candidate coords:
            //      issued before the butterfly so the L2 hit overlaps it ----
            const int    si = ci;
            const float* pc = P + (size_t)(unsigned)si * 3;
            const float px = pc[0];
            const float py = pc[1];
            const float pz = pc[2];

            // ---- 64-quarter argmax butterfly (DPP/permlane transport) ----
            argmax64(cd, ci, hi_half);

            // ---- out write: independent of the coord chain ----
            if (lane == 0 && blk == 0) out[g * NPOINTS + it + 1] = ci;

            // ---- winning lane -> broadcast its prefetched coords.
            //      Candidate indices unique across all 64 quarters
            //      (disjoint tid partitions). ----
            const unsigned long long mb = __ballot(si == ci);
            const int wl = (__ffsll(mb) - 1) & 63;
            qxf = __int_as_float(
                __builtin_amdgcn_readlane(__float_as_int(px), wl));
            qyf = __int_as_float(
                __builtin_amdgcn_readlane(__float_as_int(py), wl));
            qzf = __int_as_float(
                __builtin_amdgcn_readlane(__float_as_int(pz), wl));

            // ---- LDS mailbox: 3 tagged coord words ----
            if (lane < 3) {
                const unsigned coord =
                    (lane == 0) ? (unsigned)__float_as_int(qxf)
                  : (lane == 1) ? (unsigned)__float_as_int(qyf)
                                : (unsigned)__float_as_int(qzf);
                __hip_atomic_store(&s_mail[par][lane],
                                   ((unsigned long long)coord << 32)
                                 | (unsigned long long)tag,
                                   __ATOMIC_RELAXED,
                                   __HIP_MEMORY_SCOPE_WORKGROUP);
            }
        }

        // ---- winner coords from registers/LDS; no dependent P[wi] fetch ----
        qx = (double)qxf; qy = (double)qyf; qz = (double)qzf;
    }
}

extern "C" void kernel_launch(void* const* d_in, const int* in_sizes, int n_in,
                              void* d_out, int out_size, void* d_ws, size_t ws_size,
                              hipStream_t stream) {
    (void)in_sizes; (void)n_in; (void)out_size; (void)ws_size;
    // d_in[0] = npoints (scalar, fixed 2048 per setup), d_in[1] = t_in
    const float* t_in = (const float*)d_in[1];
    int* out = (int*)d_out;
    unsigned long long* slots = (unsigned long long*)d_ws;  // 32 KB used

    dim3 grid(NBATCH * KBLK);
    dim3 block(THREADS);
    void* args[] = { (void*)&t_in, (void*)&out, (void*)&slots };
    hipLaunchCooperativeKernel((const void*)fps_kernel, grid, block, args, 0, stream);
}